// Round 1
// 1108.517 us; speedup vs baseline: 1.1434x; 1.1434x over previous
//
// ============================================================================
// ErnieSelfAttention (B=2,S=2048,H=1024,nh=16,hd=64, rel-key-query bias) MI355X
// Round 2: fuse scores+rowstat+probs/PV into one kernel (online softmax).
//   k0: dist_emb f32 -> bf16 (row 4095 zero pad)
//   k1: QKV GEMM (bf16 MFMA 128x128 tile), +bias, scatter q/k [b,h,s,d],
//       V TRANSPOSED [b,h,d,s] (so PV staging is a straight vector copy).
//   k2 (attn): pass A  - scores tile = QK/8 + shear(Q@Ew^T)+shear(K@Ew^T)+mask,
//                        online row max/sumexp in LDS, store p_raw=exp(s-m_run)
//                        into probs region. kd v-tiles remapped to (3-wave) so
//                        qd/kd SHARE the same Es fragments (LDS reads 16->11).
//              finalize - scale[u][tile] = exp(m_tile - m_fin) / L  (LDS only)
//              pass B   - probs = p_raw * scale (no exp), write f32 in place,
//                         stage bf16 P + Vt, PV MFMA -> ctx.
// ws layout: q(8MiB) k(8MiB) vT(8MiB) e(512KiB@24MiB) = 24.5MiB
// ============================================================================
#include <hip/hip_runtime.h>
#include <hip/hip_bf16.h>
#include <cstdint>

typedef __bf16 bf16;
typedef __attribute__((ext_vector_type(8))) __bf16 bf16x8;
typedef __attribute__((ext_vector_type(4))) float f32x4;
typedef __attribute__((ext_vector_type(4))) int i32x4;

static __device__ __forceinline__ f32x4 mfma16x16x32(bf16x8 a, bf16x8 b, f32x4 c) {
    return __builtin_amdgcn_mfma_f32_16x16x32_bf16(a, b, c, 0, 0, 0);
}

// ---------------- kernel 0: dist_emb -> bf16 (pad row 4095 with zeros) ------
__global__ __launch_bounds__(256) void cvt_e_kernel(const float* __restrict__ de,
                                                    bf16* __restrict__ e) {
    int i = blockIdx.x * 256 + threadIdx.x;        // grid = 1024*256 = 4096*64
    float v = (i < 4095 * 64) ? de[i] : 0.0f;
    e[i] = (bf16)v;
}

// ---------------- kernel 1: fused QKV projection ----------------------------
// C[4096,3072] = X[4096,1024] @ W[1024,3072] + b; scatter bf16 to q/k/v ws.
// q,k: [b,h,s,d]; v: TRANSPOSED [b,h,d,s].
__global__ __launch_bounds__(256, 2) void qkv_gemm_kernel(
        const float* __restrict__ X, const float* __restrict__ W,
        const float* __restrict__ bias,
        bf16* __restrict__ qws, bf16* __restrict__ kws, bf16* __restrict__ vws) {
    __shared__ bf16 As[128][72];        // A tile [row][k]
    __shared__ bf16 Bt[128][72];        // W tile transposed [n][k]
    __shared__ float BiasS[128];
    const int t = threadIdx.x;
    const int wave = t >> 6, lane = t & 63;
    const int q4 = lane >> 4, l16 = lane & 15;
    const int n0 = blockIdx.x * 128, m0 = blockIdx.y * 128;
    const int wi = wave >> 1, wj = wave & 1;

    if (t < 32) {
        f32x4 bv = *(const f32x4*)&bias[n0 + 4 * t];
        BiasS[4*t+0] = bv.x; BiasS[4*t+1] = bv.y;
        BiasS[4*t+2] = bv.z; BiasS[4*t+3] = bv.w;
    }

    f32x4 acc[4][4];
    #pragma unroll
    for (int a = 0; a < 4; ++a)
        #pragma unroll
        for (int b = 0; b < 4; ++b)
            acc[a][b] = (f32x4){0.f, 0.f, 0.f, 0.f};

    for (int kb = 0; kb < 16; ++kb) {
        const int k0 = kb * 64;
        __syncthreads();
        {   // stage A: 128 rows x 64 k, f32 -> bf16
            const int r = t >> 1, ko = (t & 1) * 32;
            const float* src = &X[(size_t)(m0 + r) * 1024 + k0 + ko];
            #pragma unroll
            for (int i = 0; i < 4; ++i) {
                f32x4 v0 = *(const f32x4*)(src + 8 * i);
                f32x4 v1 = *(const f32x4*)(src + 8 * i + 4);
                bf16x8 h;
                h[0]=(bf16)v0.x; h[1]=(bf16)v0.y; h[2]=(bf16)v0.z; h[3]=(bf16)v0.w;
                h[4]=(bf16)v1.x; h[5]=(bf16)v1.y; h[6]=(bf16)v1.z; h[7]=(bf16)v1.w;
                *(bf16x8*)&As[r][ko + 8 * i] = h;
            }
        }
        {   // stage W transposed: 64 k-rows x 128 n
            const int kr = t >> 2, nc = (t & 3) * 32;
            const float* src = &W[(size_t)(k0 + kr) * 3072 + n0 + nc];
            #pragma unroll
            for (int i = 0; i < 32; ++i) Bt[nc + i][kr] = (bf16)src[i];
        }
        __syncthreads();
        #pragma unroll
        for (int ks = 0; ks < 64; ks += 32) {
            bf16x8 af[4], bfr[4];
            #pragma unroll
            for (int ti = 0; ti < 4; ++ti)
                af[ti] = *(const bf16x8*)&As[wi * 64 + ti * 16 + l16][ks + q4 * 8];
            #pragma unroll
            for (int tj = 0; tj < 4; ++tj)
                bfr[tj] = *(const bf16x8*)&Bt[wj * 64 + tj * 16 + l16][ks + q4 * 8];
            #pragma unroll
            for (int ti = 0; ti < 4; ++ti)
                #pragma unroll
                for (int tj = 0; tj < 4; ++tj)
                    acc[ti][tj] = mfma16x16x32(af[ti], bfr[tj], acc[ti][tj]);
        }
    }
    // epilogue: +bias, cvt bf16, scatter by (which,h,d); V transposed.
    #pragma unroll
    for (int ti = 0; ti < 4; ++ti) {
        #pragma unroll
        for (int tj = 0; tj < 4; ++tj) {
            const int coll = wj * 64 + tj * 16 + l16;
            const int col = n0 + coll;
            const int which = col >> 10;
            const int hh = (col >> 6) & 15;
            const int dd = col & 63;
            #pragma unroll
            for (int r = 0; r < 4; ++r) {
                const int row = m0 + wi * 64 + ti * 16 + q4 * 4 + r;
                const int bb = row >> 11, ss = row & 2047;
                float v = acc[ti][tj][r] + BiasS[coll];
                if (which == 2) {
                    vws[((size_t)((bb * 16 + hh) * 64 + dd) << 11) + ss] = (bf16)v;
                } else {
                    bf16* dst = which ? kws : qws;
                    dst[((size_t)((bb * 16 + hh) * 2048 + ss) << 6) + dd] = (bf16)v;
                }
            }
        }
    }
}

// ---------------- kernel 2: fused attention (scores+softmax+PV) -------------
// grid 1024: blockIdx.x = bh*32 + (l0/64). probs written in place into `sc`.
__global__ __launch_bounds__(256, 2) void attn_kernel(
        const bf16* __restrict__ qws, const bf16* __restrict__ kws,
        const bf16* __restrict__ vtws, const bf16* __restrict__ ews,
        const float* __restrict__ mask,
        float* __restrict__ sc, float* __restrict__ out) {
    __shared__ bf16 QP[64][72];        // Q (pass A) / bf16 P (pass B)
    __shared__ bf16 KV[64][72];        // K tile (pass A) / Vt tile (pass B)
    __shared__ bf16 Es[128][72];       // distance window rows pB-63 .. pB+64
    __shared__ bf16 QDs[64][68];       // sheared: QDs[u][63-v] = q[u].E[u-v]
    __shared__ bf16 KDs[64][68];       // sheared: KDs[v][u]    = k[v].E[u-v]
    __shared__ float MskS[64];
    __shared__ float Mt[64][33];       // pass A: m at tile; finalize: scale
    __shared__ float Mrun[64];
    __shared__ float Lrun[64];
    const int t = threadIdx.x;
    const int wave = t >> 6, lane = t & 63;
    const int q4 = lane >> 4, l16 = lane & 15;
    const int w3 = 3 - wave;
    const int bh = blockIdx.x >> 5;
    const int l0 = (blockIdx.x & 31) << 6;
    const int bb = bh >> 4, hh = bh & 15;
    const bf16* qb = qws + (size_t)bh * 2048 * 64;
    const bf16* kb = kws + (size_t)bh * 2048 * 64;
    float* scb = sc + ((size_t)bh * 2048 + l0) * 2048;

    if (t < 64) { Mrun[t] = -3.0e38f; Lrun[t] = 0.f; }

    {   // stage Q once
        const int r = t >> 2, c = (t & 3) * 16;
        *(i32x4*)&QP[r][c]     = *(const i32x4*)&qb[(size_t)(l0 + r) * 64 + c];
        *(i32x4*)&QP[r][c + 8] = *(const i32x4*)&qb[(size_t)(l0 + r) * 64 + c + 8];
    }

    // ======================= pass A: scores + online stats ==================
    for (int it = 0; it < 32; ++it) {
        const int r0 = it << 6;
        const int pB = l0 - r0 + 2047;           // distance idx at u==v
        __syncthreads();                          // prev-iter LDS reads done
        {   // stage K tile
            const int r = t >> 2, c = (t & 3) * 16;
            *(i32x4*)&KV[r][c]     = *(const i32x4*)&kb[(size_t)(r0 + r) * 64 + c];
            *(i32x4*)&KV[r][c + 8] = *(const i32x4*)&kb[(size_t)(r0 + r) * 64 + c + 8];
        }
        {   // stage E window (128 rows x 64); row j <-> E[pB-63+j]
            const int j = t >> 1, c = (t & 1) * 32;
            const bf16* src = &ews[(size_t)(pB - 63 + j) * 64 + c];
            #pragma unroll
            for (int i = 0; i < 4; ++i)
                *(i32x4*)&Es[j][c + 8 * i] = *(const i32x4*)(src + 8 * i);
        }
        if (t < 16) {
            f32x4 mv = *(const f32x4*)&mask[bb * 2048 + r0 + 4 * t];
            MskS[4*t+0]=mv.x; MskS[4*t+1]=mv.y; MskS[4*t+2]=mv.z; MskS[4*t+3]=mv.w;
        }
        __syncthreads();

        f32x4 sS[4], qd[5], kd[5];
        #pragma unroll
        for (int i = 0; i < 4; ++i) sS[i] = (f32x4){0.f,0.f,0.f,0.f};
        #pragma unroll
        for (int i = 0; i < 5; ++i) { qd[i] = (f32x4){0.f,0.f,0.f,0.f};
                                      kd[i] = (f32x4){0.f,0.f,0.f,0.f}; }
        // wave = u-strip for S/QD; wave computes KD v-strip (3-wave) so that
        // qd and kd consume the SAME Es fragments (j-tiles wave..wave+4).
        #pragma unroll
        for (int ks = 0; ks < 64; ks += 32) {
            const bf16x8 aq = *(const bf16x8*)&QP[wave * 16 + l16][ks + q4 * 8];
            const bf16x8 ak = *(const bf16x8*)&KV[w3 * 16 + l16][ks + q4 * 8];
            #pragma unroll
            for (int vt = 0; vt < 4; ++vt) {
                bf16x8 bk = *(const bf16x8*)&KV[vt * 16 + l16][ks + q4 * 8];
                sS[vt] = mfma16x16x32(aq, bk, sS[vt]);
            }
            #pragma unroll
            for (int i = 0; i < 5; ++i) {   // shared j-tiles: wave..wave+4
                bf16x8 be = *(const bf16x8*)&Es[(wave + i) * 16 + l16][ks + q4 * 8];
                qd[i] = mfma16x16x32(aq, be, qd[i]);
                kd[i] = mfma16x16x32(ak, be, kd[i]);
            }
        }
        // sheared stores: keep only the consumed parallelogram (64x64 each)
        #pragma unroll
        for (int i = 0; i < 5; ++i) {
            #pragma unroll
            for (int r = 0; r < 4; ++r) {
                const int uq = wave * 16 + q4 * 4 + r;        // QD row
                const int tq = i * 16 + l16 - (q4 * 4 + r);   // j - u
                if (tq >= 0 && tq < 64) QDs[uq][tq] = (bf16)qd[i][r];
                const int uk = w3 * 16 + q4 * 4 + r;          // KD row (v)
                const int tk = i * 16 + l16 + (q4 * 4 + r) - 15;  // j + v - 63
                if (tk >= 0 && tk < 64) KDs[uk][tk] = (bf16)kd[i][r];
            }
        }
        __syncthreads();
        // combine + online softmax + store p_raw = exp(s - m_running)
        float sv[4][4];
        #pragma unroll
        for (int vt = 0; vt < 4; ++vt)
            #pragma unroll
            for (int r = 0; r < 4; ++r) {
                const int u = wave * 16 + q4 * 4 + r;
                const int v = vt * 16 + l16;
                sv[vt][r] = sS[vt][r] * 0.125f
                          + (float)QDs[u][63 - v] + (float)KDs[v][u] + MskS[v];
            }
        #pragma unroll
        for (int r = 0; r < 4; ++r) {
            const int u = wave * 16 + q4 * 4 + r;
            float tm = fmaxf(fmaxf(sv[0][r], sv[1][r]), fmaxf(sv[2][r], sv[3][r]));
            tm = fmaxf(tm, __shfl_xor(tm, 1, 64));
            tm = fmaxf(tm, __shfl_xor(tm, 2, 64));
            tm = fmaxf(tm, __shfl_xor(tm, 4, 64));
            tm = fmaxf(tm, __shfl_xor(tm, 8, 64));
            const float mo = Mrun[u];
            const float mn = fmaxf(mo, tm);
            float ts = 0.f;
            #pragma unroll
            for (int vt = 0; vt < 4; ++vt) {
                const float p = __expf(sv[vt][r] - mn);
                scb[(size_t)u * 2048 + r0 + vt * 16 + l16] = p;
                ts += p;
            }
            ts += __shfl_xor(ts, 1, 64);
            ts += __shfl_xor(ts, 2, 64);
            ts += __shfl_xor(ts, 4, 64);
            ts += __shfl_xor(ts, 8, 64);
            if (l16 == 0) {
                Lrun[u] = Lrun[u] * __expf(mo - mn) + ts;
                Mrun[u] = mn;
                Mt[u][it] = mn;
            }
        }
    }

    // ======================= finalize scales ================================
    __syncthreads();
    if (t < 64) {
        const float mf = Mrun[t];
        const float rl = 1.0f / Lrun[t];
        #pragma unroll
        for (int it = 0; it < 32; ++it)
            Mt[t][it] = __expf(Mt[t][it] - mf) * rl;
    }

    // ======================= pass B: probs + PV =============================
    f32x4 acc[4];
    #pragma unroll
    for (int dt = 0; dt < 4; ++dt) acc[dt] = (f32x4){0.f,0.f,0.f,0.f};

    for (int it = 0; it < 32; ++it) {
        const int r0 = it << 6;
        __syncthreads();
        {   // read p_raw, scale, write final probs, stage bf16 P
            const int rr = t >> 2, c = (t & 3) * 16;
            const float s = Mt[rr][it];
            float* srow = &scb[(size_t)rr * 2048 + r0 + c];
            f32x4 p0 = *(const f32x4*)(srow + 0);
            f32x4 p1 = *(const f32x4*)(srow + 4);
            f32x4 p2 = *(const f32x4*)(srow + 8);
            f32x4 p3 = *(const f32x4*)(srow + 12);
            p0.x*=s; p0.y*=s; p0.z*=s; p0.w*=s;
            p1.x*=s; p1.y*=s; p1.z*=s; p1.w*=s;
            p2.x*=s; p2.y*=s; p2.z*=s; p2.w*=s;
            p3.x*=s; p3.y*=s; p3.z*=s; p3.w*=s;
            *(f32x4*)(srow + 0)  = p0;
            *(f32x4*)(srow + 4)  = p1;
            *(f32x4*)(srow + 8)  = p2;
            *(f32x4*)(srow + 12) = p3;
            bf16x8 h0, h1;
            h0[0]=(bf16)p0.x; h0[1]=(bf16)p0.y; h0[2]=(bf16)p0.z; h0[3]=(bf16)p0.w;
            h0[4]=(bf16)p1.x; h0[5]=(bf16)p1.y; h0[6]=(bf16)p1.z; h0[7]=(bf16)p1.w;
            h1[0]=(bf16)p2.x; h1[1]=(bf16)p2.y; h1[2]=(bf16)p2.z; h1[3]=(bf16)p2.w;
            h1[4]=(bf16)p3.x; h1[5]=(bf16)p3.y; h1[6]=(bf16)p3.z; h1[7]=(bf16)p3.w;
            *(bf16x8*)&QP[rr][c]     = h0;
            *(bf16x8*)&QP[rr][c + 8] = h1;
        }
        {   // stage Vt tile: straight vector copy (V is [b,h,d,s])
            const int dr = t >> 2, c = (t & 3) * 16;
            const bf16* src = &vtws[(((size_t)bh * 64 + dr) << 11) + r0 + c];
            *(i32x4*)&KV[dr][c]     = *(const i32x4*)(src);
            *(i32x4*)&KV[dr][c + 8] = *(const i32x4*)(src + 8);
        }
        __syncthreads();
        #pragma unroll
        for (int ks = 0; ks < 64; ks += 32) {
            const bf16x8 ap = *(const bf16x8*)&QP[wave * 16 + l16][ks + q4 * 8];
            #pragma unroll
            for (int dt = 0; dt < 4; ++dt) {
                bf16x8 bv = *(const bf16x8*)&KV[dt * 16 + l16][ks + q4 * 8];
                acc[dt] = mfma16x16x32(ap, bv, acc[dt]);
            }
        }
    }
    #pragma unroll
    for (int dt = 0; dt < 4; ++dt) {
        #pragma unroll
        for (int r = 0; r < 4; ++r) {
            const int u = wave * 16 + q4 * 4 + r;
            const int d = dt * 16 + l16;
            out[(size_t)(bb * 2048 + l0 + u) * 1024 + hh * 64 + d] = acc[dt][r];
        }
    }
}

// ---------------- launcher --------------------------------------------------
extern "C" void kernel_launch(void* const* d_in, const int* in_sizes, int n_in,
                              void* d_out, int out_size, void* d_ws, size_t ws_size,
                              hipStream_t stream) {
    const float* hidden = (const float*)d_in[0];   // [2,2048,1024]
    const float* mask   = (const float*)d_in[1];   // [2,1,1,2048]
    const float* qkv_w  = (const float*)d_in[2];   // [1024,3072]
    const float* qkv_b  = (const float*)d_in[3];   // [3072]
    const float* demb   = (const float*)d_in[4];   // [4095,64]

    float* ctx   = (float*)d_out;                       // 4,194,304 f32
    float* probs = ctx + (size_t)2 * 2048 * 1024;       // 134,217,728 f32

    char* ws = (char*)d_ws;                             // needs 25,690,112 B
    bf16*  qws  = (bf16*)(ws);
    bf16*  kws  = (bf16*)(ws + 8388608);
    bf16*  vtws = (bf16*)(ws + 16777216);               // V transposed [b,h,d,s]
    bf16*  ews  = (bf16*)(ws + 25165824);               // 4096*64 bf16

    hipLaunchKernelGGL(cvt_e_kernel, dim3(1024), dim3(256), 0, stream, demb, ews);
    hipLaunchKernelGGL(qkv_gemm_kernel, dim3(24, 32), dim3(256), 0, stream,
                       hidden, qkv_w, qkv_b, qws, kws, vtws);
    hipLaunchKernelGGL(attn_kernel, dim3(1024), dim3(256), 0, stream,
                       qws, kws, vtws, ews, mask, probs, ctx);
}